// Round 2
// baseline (27.805 us; speedup 1.0000x reference)
//
#include <hip/hip_runtime.h>

// QuantizedEmbedding: out[t, d] = (qweight[input[t], d] - zeros[input[t]]) * scales[input[t]]
// B*S = 16384 tokens, DIM = 1024, VOCAB = 128000. Output fp32.
// Memory-bound gather: ~64 MiB read (gathered rows) + 64 MiB write -> floor ~19-21 us.
//
// Structure: one wave (64 lanes) per token; each lane does 4 independent 16B
// nontemporal loads + 4 nontemporal 16B stores (MLP=4 per thread). 256-thread
// blocks cover 4 tokens each.

constexpr int DIM = 1024;

typedef int   int4v   __attribute__((ext_vector_type(4)));
typedef float float4v __attribute__((ext_vector_type(4)));

__global__ __launch_bounds__(256) void qembed_kernel(
    const int*   __restrict__ input,    // [NTOK]
    const int*   __restrict__ qweight,  // [VOCAB, DIM]
    const float* __restrict__ scales,   // [VOCAB]
    const float* __restrict__ zeros,    // [VOCAB]
    float*       __restrict__ out,      // [NTOK, DIM]
    int ntok)
{
    const int tok  = blockIdx.x * 4 + (threadIdx.x >> 6);  // one wave per token
    const int lane = threadIdx.x & 63;
    if (tok >= ntok) return;

    const int row = input[tok];                 // wave-uniform
    const float scale = scales[row];
    const float zero  = zeros[row];

    const int4v*  qrow = reinterpret_cast<const int4v*>(qweight + (size_t)row * DIM);
    float4v*      orow = reinterpret_cast<float4v*>(out + (size_t)tok * DIM);

    // DIM=1024 -> 256 int4 chunks; 64 lanes x 4 chunks. Issue all 4 loads
    // before any use so 4 vmem ops are in flight per lane.
    int4v q0 = __builtin_nontemporal_load(qrow + lane);
    int4v q1 = __builtin_nontemporal_load(qrow + lane + 64);
    int4v q2 = __builtin_nontemporal_load(qrow + lane + 128);
    int4v q3 = __builtin_nontemporal_load(qrow + lane + 192);

    float4v o0, o1, o2, o3;
    #pragma unroll
    for (int j = 0; j < 4; ++j) {
        o0[j] = ((float)q0[j] - zero) * scale;
        o1[j] = ((float)q1[j] - zero) * scale;
        o2[j] = ((float)q2[j] - zero) * scale;
        o3[j] = ((float)q3[j] - zero) * scale;
    }

    __builtin_nontemporal_store(o0, orow + lane);
    __builtin_nontemporal_store(o1, orow + lane + 64);
    __builtin_nontemporal_store(o2, orow + lane + 128);
    __builtin_nontemporal_store(o3, orow + lane + 192);
}

extern "C" void kernel_launch(void* const* d_in, const int* in_sizes, int n_in,
                              void* d_out, int out_size, void* d_ws, size_t ws_size,
                              hipStream_t stream) {
    const int*   input   = (const int*)d_in[0];    // [B*S] int32 indices
    const int*   qweight = (const int*)d_in[1];    // [VOCAB*DIM] int32 codes
    const float* scales  = (const float*)d_in[2];  // [VOCAB]
    const float* zeros   = (const float*)d_in[3];  // [VOCAB]
    float*       out     = (float*)d_out;          // [B*S*DIM] fp32

    const int ntok = in_sizes[0];                  // 16384
    dim3 grid((ntok + 3) / 4);                     // 4 tokens (waves) per block
    dim3 block(256);
    qembed_kernel<<<grid, block, 0, stream>>>(input, qweight, scales, zeros, out, ntok);
}

// Round 3
// 25.445 us; speedup vs baseline: 1.0928x; 1.0928x over previous
//
#include <hip/hip_runtime.h>

// QuantizedEmbedding: out[t, d] = (qweight[input[t], d] - zeros[input[t]]) * scales[input[t]]
// B*S = 16384 tokens, DIM = 1024, VOCAB = 128000. Output fp32.
// Memory-bound gather: ~64 MiB read (gathered rows) + 64 MiB write -> floor ~20 us.
//
// r3 = r1 structure (best measured: one token per 256-thread block, one
// int4 load -> float4 store per thread, independent chains across waves)
// + nontemporal STORES only. Output is write-once streaming: bypassing L2
// retention for it leaves the full L2/LLC for the qweight read stream
// (duplicate rows ~6%, plus cross-replay LLC warmth). Loads stay cached.

constexpr int DIM = 1024;

typedef int   int4v   __attribute__((ext_vector_type(4)));
typedef float float4v __attribute__((ext_vector_type(4)));

__global__ __launch_bounds__(256) void qembed_kernel(
    const int*   __restrict__ input,    // [NTOK] row indices
    const int*   __restrict__ qweight,  // [VOCAB, DIM] codes in [0,256)
    const float* __restrict__ scales,   // [VOCAB]
    const float* __restrict__ zeros,    // [VOCAB]
    float*       __restrict__ out,      // [NTOK, DIM]
    int ntok)
{
    const int tok = blockIdx.x;
    if (tok >= ntok) return;

    const int row = input[tok];              // block-uniform -> scalar load
    const float scale = scales[row];
    const float zero  = zeros[row];

    const int4v* qrow = reinterpret_cast<const int4v*>(qweight + (size_t)row * DIM);
    float4v*     orow = reinterpret_cast<float4v*>(out + (size_t)tok * DIM);

    const int t = threadIdx.x;               // 0..255 -> 256 x 16B = 4 KiB row
    int4v q = qrow[t];                       // cached load (L2/LLC retention)
    float4v o;
    o.x = ((float)q.x - zero) * scale;
    o.y = ((float)q.y - zero) * scale;
    o.z = ((float)q.z - zero) * scale;
    o.w = ((float)q.w - zero) * scale;
    __builtin_nontemporal_store(o, orow + t);  // streaming store, don't pollute L2
}

extern "C" void kernel_launch(void* const* d_in, const int* in_sizes, int n_in,
                              void* d_out, int out_size, void* d_ws, size_t ws_size,
                              hipStream_t stream) {
    const int*   input   = (const int*)d_in[0];    // [B*S] int32 indices
    const int*   qweight = (const int*)d_in[1];    // [VOCAB*DIM] int32 codes
    const float* scales  = (const float*)d_in[2];  // [VOCAB]
    const float* zeros   = (const float*)d_in[3];  // [VOCAB]
    float*       out     = (float*)d_out;          // [B*S*DIM] fp32

    const int ntok = in_sizes[0];                  // 16384
    dim3 grid(ntok);
    dim3 block(256);
    qembed_kernel<<<grid, block, 0, stream>>>(input, qweight, scales, zeros, out, ntok);
}